// Round 7
// baseline (215.566 us; speedup 1.0000x reference)
//
#include <hip/hip_runtime.h>
#include <hip/hip_bf16.h>

// Problem constants
#define B_    8
#define CIN   128
#define H_    64
#define W_    64
#define COUT  128
#define K_    16
#define HO    61
#define WO    61
#define HW_   (HO * WO)          // 3721
#define KKTOT (CIN * K_)         // 2048
#define KKQ   512                // kk per quarter (Bs = 16 KB)
#define TILW4 33                 // tile row stride in c4-words (pad +1)
#define TILWDS (16 * TILW4)      // 528 c4-words per buffer (8448 B)

typedef short bf16x8 __attribute__((ext_vector_type(8)));
typedef float f32x4  __attribute__((ext_vector_type(4)));
typedef float f32x2u __attribute__((ext_vector_type(2), aligned(4)));

// Pre-flip weight (transposed-conv: k' = 15-k), bf16.  A[o][c*16+k] = w[o][c][15-k]
__global__ __launch_bounds__(256) void prep_weight(const float* __restrict__ w,
                                                   __hip_bfloat16* __restrict__ A) {
    int idx = blockIdx.x * 256 + threadIdx.x;
    int o   = idx >> 11;
    int rem = idx & 2047;
    int c   = rem >> 4;
    int k   = rem & 15;
    A[idx]  = __float2bfloat16(w[(o << 11) + (c << 4) + (15 - k)]);
}

// Block = 16 pixels of one (b,ho) row segment x 128 couts. 256 thr = (pix, tap).
// Channel-interleaved LDS tile: float4 word = 4 channels of one (row,col).
// One ds_read_b128 gathers a bilinear corner for 4 channels -> divergent-gather
// instruction count halves vs channel-planar. Double-buffered tile -> single
// barrier per 4-channel group. LDS 33.3 KB -> 4 blocks/CU.
__global__ __launch_bounds__(256, 4) void deform_main(
        const float* __restrict__ inp, const float* __restrict__ off,
        const float* __restrict__ msk, const __hip_bfloat16* __restrict__ A,
        const float* __restrict__ bias, float* __restrict__ out) {

    __shared__ __align__(16) __hip_bfloat16 Bs[16 * KKQ];   // 16 KB
    __shared__ __align__(16) f32x4 tile[2][TILWDS];         // 16.9 KB

    const int t   = threadIdx.x;
    const int pix = t & 15;
    const int k   = t >> 4;            // tap 0..15

    // ---- block decode: bid&7 = batch (XCD/L2 pinning) ----
    const int bid = blockIdx.x;
    const int b   = bid & 7;
    const int g   = bid >> 3;
    const int ho  = g >> 2;
    const int wt  = (g & 3) << 4;
    const int wo  = wt + pix;
    const bool pvalid = (wo < WO);
    const int wo_c = pvalid ? wo : (WO - 1);
    const int r    = ho * WO + wo_c;

    // ---- window: 16 rows x 32 cols, margin ~6 sigma ----
    const int ry_lo = min(max(ho - 6, 0), H_ - 16);
    const int cx_lo = min(max(wt - 6, 0), W_ - 32) & ~3;

    // ---- per-(pixel,tap) sampling params ----
    const int ki = k >> 2, kj = k & 3;
    const size_t offb = (size_t)b * (2 * K_ * HW_);
    float dy = off[offb + (size_t)(2 * k)     * HW_ + r];
    float dx = off[offb + (size_t)(2 * k + 1) * HW_ + r];
    float mm = msk[(size_t)b * (K_ * HW_) + (size_t)k * HW_ + r];
    if (!pvalid) mm = 0.0f;

    float y   = dy + (float)(ki + ho);
    float x   = dx + (float)(kj + wo_c);
    float y0f = floorf(y), x0f = floorf(x);
    float wy  = y - y0f,   wx  = x - x0f;
    int y0 = (int)y0f, x0 = (int)x0f;
    int y1 = y0 + 1,   x1 = x0 + 1;

    float wy0v = (1.0f - wy) * ((y0 >= 0 && y0 < H_) ? mm : 0.0f);
    float wy1v = wy          * ((y1 >= 0 && y1 < H_) ? mm : 0.0f);
    int cy0 = min(max(y0, 0), H_ - 1), cy1 = min(max(y1, 0), H_ - 1);

    float wx0v = (1.0f - wx) * ((x0 >= 0 && x0 < W_) ? 1.0f : 0.0f);
    float wx1v = wx          * ((x1 >= 0 && x1 < W_) ? 1.0f : 0.0f);
    int xb = min(max(x0, 0), W_ - 2);
    int tsh = x0 - xb;                 // -1,0,1 (else both x-weights are 0)
    float a0 = (tsh == 0) ? wx0v : ((tsh == -1) ? wx1v : 0.0f);
    float a1 = (tsh == 0) ? wx1v : ((tsh ==  1) ? wx0v : 0.0f);

    const float b00 = wy0v * a0, b01 = wy0v * a1;
    const float b10 = wy1v * a0, b11 = wy1v * a1;
    const int ad0 = cy0 * W_ + xb;     // exact global fallback addrs
    const int ad1 = cy1 * W_ + xb;

    // tile coords + in-window test (fallback handles the ~6-sigma tail exactly)
    int t0 = cy0 - ry_lo, t1 = cy1 - ry_lo, u = xb - cx_lo;
    const bool intile = (t0 >= 0) & (t0 < 16) & (t1 >= 0) & (t1 < 16) &
                        (u >= 0) & (u <= 30);
    const float l00 = intile ? b00 : 0.0f, l01 = intile ? b01 : 0.0f;
    const float l10 = intile ? b10 : 0.0f, l11 = intile ? b11 : 0.0f;
    const int tc0 = min(max(t0, 0), 15) * TILW4 + min(max(u, 0), 30);
    const int tc1 = min(max(t1, 0), 15) * TILW4 + min(max(u, 0), 30);

    const float* pin = inp + (size_t)b * (CIN * H_ * W_);

    // ---- staging geometry: thread covers (row, col) and (row+8, col) ----
    const int scol = t & 31;
    const int srow = t >> 5;           // 0..7
    int soff[2], lword[2];
    #pragma unroll
    for (int j = 0; j < 2; ++j) {
        int row  = srow + 8 * j;
        soff[j]  = (ry_lo + row) * W_ + cx_lo + scol;   // channel-0 dword offset
        lword[j] = row * TILW4 + scol;                  // c4-word index
    }

    // MFMA identity
    const int lane = t & 63;
    const int wv   = t >> 6;
    const int quad = lane >> 4;
    const int mrow = lane & 15;        // == pix
    const int q8   = quad << 3;
    const __hip_bfloat16* Arow0 = A + ((size_t)(wv * 32 + mrow) << 11);
    const __hip_bfloat16* Arow1 = Arow0 + (16 << 11);
    const int brot = mrow << 3;

    f32x4 acc0 = {0.f, 0.f, 0.f, 0.f};
    f32x4 acc1 = {0.f, 0.f, 0.f, 0.f};

    // ---- prologue: group 0 -> tile[0]; prefetch group 1 into pf ----
    float pf[8];
    #pragma unroll
    for (int j = 0; j < 2; ++j)
        #pragma unroll
        for (int c = 0; c < 4; ++c)
            pf[j * 4 + c] = pin[(c << 12) + soff[j]];
    #pragma unroll
    for (int j = 0; j < 2; ++j) {
        f32x4 wd = {pf[j * 4 + 0], pf[j * 4 + 1], pf[j * 4 + 2], pf[j * 4 + 3]};
        tile[0][lword[j]] = wd;
    }
    #pragma unroll
    for (int j = 0; j < 2; ++j)
        #pragma unroll
        for (int c = 0; c < 4; ++c)
            pf[j * 4 + c] = pin[(1 << 14) + (c << 12) + soff[j]];
    __syncthreads();

    #pragma unroll 1
    for (int q = 0; q < 4; ++q) {
        #pragma unroll 1
        for (int gi = 0; gi < 8; ++gi) {
            const int gidx  = (q << 3) + gi;       // current group (tile[gidx&1])
            const int cbase = gidx << 2;
            const int gn2   = (gidx + 2) & 31;     // prefetch 2 ahead

            // write prefetched group gidx+1 into the other buffer
            f32x4* tw = tile[(gidx + 1) & 1];
            #pragma unroll
            for (int j = 0; j < 2; ++j) {
                f32x4 wd = {pf[j * 4 + 0], pf[j * 4 + 1], pf[j * 4 + 2], pf[j * 4 + 3]};
                tw[lword[j]] = wd;
            }
            // prefetch group gidx+2 into registers (covers a full segment)
            const float* gb2 = pin + ((size_t)gn2 << 14);
            #pragma unroll
            for (int j = 0; j < 2; ++j)
                #pragma unroll
                for (int c = 0; c < 4; ++c)
                    pf[j * 4 + c] = gb2[(c << 12) + soff[j]];

            // gather 4 corners x 4 channels from tile[gidx&1]
            const f32x4* tb = tile[gidx & 1];
            f32x4 w00 = tb[tc0], w01 = tb[tc0 + 1];
            f32x4 w10 = tb[tc1], w11 = tb[tc1 + 1];
            float s[4];
            #pragma unroll
            for (int c = 0; c < 4; ++c)
                s[c] = l00 * w00[c] + l01 * w01[c] + l10 * w10[c] + l11 * w11[c];
            if (!intile) {             // exec-skipped ~always; exact tail
                #pragma unroll
                for (int c = 0; c < 4; ++c) {
                    const float* p = pin + ((size_t)(cbase + c) << 12);
                    f32x2u h0 = *(const f32x2u*)(const void*)(p + ad0);
                    f32x2u h1 = *(const f32x2u*)(const void*)(p + ad1);
                    s[c] += b00 * h0[0] + b01 * h0[1] + b10 * h1[0] + b11 * h1[1];
                }
            }
            #pragma unroll
            for (int c = 0; c < 4; ++c) {
                int kkl = (((cbase + c) & 31) << 4) + k;
                Bs[(pix << 9) + ((kkl + (pix << 3)) & (KKQ - 1))] = __float2bfloat16(s[c]);
            }
            __syncthreads();           // single barrier per group
        }

        // ---- MFMA over this quarter's 512 kk ----
        const __hip_bfloat16* Aq0 = Arow0 + (q << 9);
        const __hip_bfloat16* Aq1 = Arow1 + (q << 9);
        const __hip_bfloat16* bsb = &Bs[mrow << 9];
        #pragma unroll 4
        for (int it = 0; it < 16; ++it) {
            int kk0 = (it << 5) + q8;
            bf16x8 av0 = *(const bf16x8*)(const void*)(Aq0 + kk0);
            bf16x8 av1 = *(const bf16x8*)(const void*)(Aq1 + kk0);
            bf16x8 bb  = *(const bf16x8*)(const void*)(bsb + ((kk0 + brot) & (KKQ - 1)));
            acc0 = __builtin_amdgcn_mfma_f32_16x16x32_bf16(av0, bb, acc0, 0, 0, 0);
            acc1 = __builtin_amdgcn_mfma_f32_16x16x32_bf16(av1, bb, acc1, 0, 0, 0);
        }
        __syncthreads();               // Bs reads done before next quarter's writes
    }

    // ---- epilogue: C/D col=lane&15 (pixel), row=quad*4+j (cout) ----
    if (pvalid) {
        size_t outb = (size_t)b * (COUT * HW_) + r;
        #pragma unroll
        for (int j = 0; j < 4; ++j) {
            int o = wv * 32 + quad * 4 + j;
            out[outb + (size_t)o        * HW_] = acc0[j] + bias[o];
            out[outb + (size_t)(o + 16) * HW_] = acc1[j] + bias[o + 16];
        }
    }
}

extern "C" void kernel_launch(void* const* d_in, const int* in_sizes, int n_in,
                              void* d_out, int out_size, void* d_ws, size_t ws_size,
                              hipStream_t stream) {
    const float* inp  = (const float*)d_in[0];
    const float* off  = (const float*)d_in[1];
    const float* msk  = (const float*)d_in[2];
    const float* wgt  = (const float*)d_in[3];
    const float* bias = (const float*)d_in[4];
    float* out = (float*)d_out;

    __hip_bfloat16* A = (__hip_bfloat16*)d_ws;   // 512 KB

    prep_weight<<<(COUT * KKTOT) / 256, 256, 0, stream>>>(wgt, A);

    int nblk = B_ * HO * 4;            // 1952 (bid&7 = batch)
    deform_main<<<nblk, 256, 0, stream>>>(inp, off, msk, A, bias, out);
}